// Round 11
// baseline (257.367 us; speedup 1.0000x reference)
//
#include <hip/hip_runtime.h>
#include <math.h>

#define CIN   256
#define COUT  256
#define H     64
#define W     64
#define HW    4096
#define KK    9
#define KC    2304
#define NOFF  27
#define B_    4
#define EPS   1e-5f
#define OM3S  (B_ * NOFF * HW)   // floats per offconv partial buffer

typedef __attribute__((ext_vector_type(4))) float f32x4;
typedef __attribute__((ext_vector_type(8))) short s16x8;

static __device__ __forceinline__ unsigned short f2bf(float f) {
  unsigned u = __builtin_bit_cast(unsigned, f);
  u += 0x7FFF + ((u >> 16) & 1);
  return (unsigned short)(u >> 16);
}
static __device__ __forceinline__ float bflo(unsigned u) {
  return __builtin_bit_cast(float, u << 16);
}
static __device__ __forceinline__ float bfhi(unsigned u) {
  return __builtin_bit_cast(float, u & 0xffff0000u);
}
static __device__ __forceinline__ unsigned packbf(float lo, float hi) {
  unsigned ul = __builtin_bit_cast(unsigned, lo);
  unsigned uh = __builtin_bit_cast(unsigned, hi);
  ul += 0x7FFF + ((ul >> 16) & 1);
  uh += 0x7FFF + ((uh >> 16) & 1);
  return (ul >> 16) | (uh & 0xffff0000u);
}
static __device__ __forceinline__ void gl2lds16(const void* g, void* l) {
  __builtin_amdgcn_global_load_lds(
      (const __attribute__((address_space(1))) unsigned int*)g,
      (__attribute__((address_space(3))) unsigned int*)l, 16, 0, 0);
}

// ---------------------------------------------------------------------------
// prep: fused xprep + weight prep + gstat zero.
//  blocks [0,256):     x NCHW f32 -> xT NHWC bf16
//  blocks [256,544):   wBf main-weight MFMA-B-fragment order:
//                      packet p=(k2*16+tn)*64+lane; elem j: co=tn*16+(lane&15),
//                      k'=k2*32+(lane>>4)*8+j, k'=kt*256+c
//  blocks [544,580):   wOBf offset-weight fragment order (oc>=27 zero)
//  block 580:          zero gstat
// ---------------------------------------------------------------------------
__global__ __launch_bounds__(256) void prep_kernel(
    const float* __restrict__ x, const float* __restrict__ w,
    const float* __restrict__ w_off, unsigned short* __restrict__ xT,
    unsigned short* __restrict__ wBf, unsigned short* __restrict__ wOBf,
    float* __restrict__ gstat) {
  int bi = blockIdx.x;
  int t = threadIdx.x;
  if (bi < 256) {
    __shared__ unsigned short tile[64][272];
    int b = bi >> 6, y = bi & 63;
    const float* src = x + (size_t)b * CIN * HW + y * W;
    for (int r = 0; r < 64; ++r) {
      int idx = r * 256 + t;
      int c = idx >> 6, ww = idx & 63;
      tile[ww][c] = f2bf(src[(size_t)c * HW + ww]);
    }
    __syncthreads();
    unsigned short* dst = xT + ((size_t)(b * 64 + y) * 64) * 256;
    for (int r = 0; r < 8; ++r) {
      int idx = r * 2048 + t * 8;
      int ww = idx >> 8, c = idx & 255;
      *(uint4*)(dst + idx) = *(const uint4*)&tile[ww][c];
    }
  } else if (bi < 544) {
    int pkt = (bi - 256) * 256 + t;        // [0, 73728)
    int lane = pkt & 63;
    int tn = (pkt >> 6) & 15;
    int k2 = pkt >> 10;
    int co = tn * 16 + (lane & 15);
    int kb = k2 * 32 + (lane >> 4) * 8;
    unsigned short v[8];
#pragma unroll
    for (int j = 0; j < 8; ++j) {
      int kk = kb + j;
      int kt = kk >> 8, c = kk & 255;
      v[j] = f2bf(w[(co * 256 + c) * 9 + kt]);
    }
    *(uint4*)&wBf[(size_t)pkt * 8] = *(const uint4*)v;
  } else if (bi < 580) {
    int pkt = (bi - 544) * 256 + t;        // [0, 9216)
    int lane = pkt & 63;
    int tn = (pkt >> 6) & 1;
    int k2 = pkt >> 7;
    int oc = tn * 16 + (lane & 15);
    int kb = k2 * 32 + (lane >> 4) * 8;
    unsigned short v[8];
#pragma unroll
    for (int j = 0; j < 8; ++j) {
      int kk = kb + j;
      int kt = kk >> 8, c = kk & 255;
      v[j] = (oc < NOFF) ? f2bf(w_off[(oc * 256 + c) * 9 + kt]) : (unsigned short)0;
    }
    *(uint4*)&wOBf[(size_t)pkt * 8] = *(const uint4*)v;
  } else {
    if (t < 128) gstat[t] = 0.f;
  }
}

// ---------------------------------------------------------------------------
// offconv: tap-split x3 partials, no LDS/barriers. grid 768.
// ---------------------------------------------------------------------------
__global__ __launch_bounds__(256) void offconv_mfma_kernel(
    const unsigned short* __restrict__ xT, const unsigned short* __restrict__ wOBf,
    float* __restrict__ om3) {
  int bi = blockIdx.x;
  int ts = bi >> 8;
  int row = bi & 255;
  int b = row >> 6, i = row & 63;
  int t = threadIdx.x, lane = t & 63, wv = t >> 6;
  int lr = lane & 15, lq = lane >> 4;
  int p = wv * 16 + lr;
  const unsigned short* xb = xT + (size_t)b * (HW * 256);
  f32x4 acc[2] = {};

  for (int kc = 0; kc < 3; ++kc) {
    int kt = ts * 3 + kc;
    int ky = kt / 3, kx = kt % 3;
    int yy = i - 1 + ky, xx = p - 1 + kx;
    bool ok = ((unsigned)yy < 64u) && ((unsigned)xx < 64u);
    const unsigned short* ap = xb + ((ok ? yy * 64 + xx : 0) << 8) + lq * 8;
#pragma unroll
    for (int c8 = 0; c8 < 8; ++c8) {
      uint4 av = uint4{0, 0, 0, 0};
      if (ok) av = *(const uint4*)(ap + c8 * 32);
      int k2 = kt * 8 + c8;
      s16x8 a = __builtin_bit_cast(s16x8, av);
      s16x8 b0 = *(const s16x8*)(wOBf + ((((k2 * 2 + 0) << 6) | lane) << 3));
      s16x8 b1 = *(const s16x8*)(wOBf + ((((k2 * 2 + 1) << 6) | lane) << 3));
      acc[0] = __builtin_amdgcn_mfma_f32_16x16x32_bf16(a, b0, acc[0], 0, 0, 0);
      acc[1] = __builtin_amdgcn_mfma_f32_16x16x32_bf16(a, b1, acc[1], 0, 0, 0);
    }
  }
#pragma unroll
  for (int tn = 0; tn < 2; ++tn) {
    int oc = tn * 16 + lr;
    if (oc < NOFF) {
      float* ob = om3 + (size_t)ts * OM3S + ((b * NOFF + oc) << 12) + i * 64 + wv * 16;
#pragma unroll
      for (int r = 0; r < 4; ++r) ob[lq * 4 + r] = acc[tn][r];
    }
  }
}

// ---------------------------------------------------------------------------
// sampler: build im2col A[pix][k'] bf16 (k' = kt*256 + c). grid 512.
// ---------------------------------------------------------------------------
__global__ __launch_bounds__(256, 2) void sampler_kernel(
    const unsigned short* __restrict__ xT, const float* __restrict__ om3,
    const float* __restrict__ b_off, unsigned short* __restrict__ Aout) {
  __shared__ float tapw[32][KK][4];
  __shared__ int   tapc[32][KK][4];
  int bi = blockIdx.x;
  int b = bi >> 7, i = (bi >> 1) & 63, j0 = (bi & 1) * 32;
  int t = threadIdx.x;
  const unsigned short* xb = xT + (size_t)b * (HW * 256);

  for (int idx = t; idx < 32 * KK; idx += 256) {
    int p = idx / KK, k = idx % KK;
    int pix = i * 64 + j0 + p;
    size_t o = (size_t)(b * NOFF) * HW + pix;
    float offy = om3[o + k * HW] + om3[OM3S + o + k * HW] +
                 om3[2 * OM3S + o + k * HW] + b_off[k];
    float offx = om3[o + (9 + k) * HW] + om3[OM3S + o + (9 + k) * HW] +
                 om3[2 * OM3S + o + (9 + k) * HW] + b_off[9 + k];
    float mval = om3[o + (18 + k) * HW] + om3[OM3S + o + (18 + k) * HW] +
                 om3[2 * OM3S + o + (18 + k) * HW] + b_off[18 + k];
    float mask = 1.f / (1.f + __expf(-mval));
    float py = (float)(i - 1 + k / 3) + offy;
    float px = (float)(j0 + p - 1 + k % 3) + offx;
    float y0f = floorf(py), x0f = floorf(px);
    float wy1 = py - y0f, wx1 = px - x0f;
    int y0 = (int)y0f, x0 = (int)x0f;
    bool y0ok = (unsigned)y0 < 64u, y1ok = (unsigned)(y0 + 1) < 64u;
    bool x0ok = (unsigned)x0 < 64u, x1ok = (unsigned)(x0 + 1) < 64u;
    tapw[p][k][0] = (1.f - wy1) * (1.f - wx1) * mask * (float)(y0ok && x0ok);
    tapw[p][k][1] = (1.f - wy1) * wx1 * mask * (float)(y0ok && x1ok);
    tapw[p][k][2] = wy1 * (1.f - wx1) * mask * (float)(y1ok && x0ok);
    tapw[p][k][3] = wy1 * wx1 * mask * (float)(y1ok && x1ok);
    int y0c = min(max(y0, 0), 63), y1c = min(max(y0 + 1, 0), 63);
    int x0c = min(max(x0, 0), 63), x1c = min(max(x0 + 1, 0), 63);
    tapc[p][k][0] = (y0c * 64 + x0c) * 256;
    tapc[p][k][1] = (x1c - x0c) * 256;
    tapc[p][k][2] = (y1c - y0c) * 64 * 256;
    tapc[p][k][3] = 0;
  }
  __syncthreads();

  int p = t >> 3, s = t & 7;
  int gpix = b * 4096 + i * 64 + j0 + p;
  unsigned short* arow = Aout + (size_t)gpix * KC;

  for (int kt = 0; kt < KK; ++kt) {
    f32x4 tw = *(const f32x4*)&tapw[p][kt][0];
    float w00 = tw[0], w01 = tw[1], w10 = tw[2], w11 = tw[3];
    int4 tc = *(const int4*)&tapc[p][kt][0];
    const unsigned short* c00 = xb + tc.x + s * 8;
    int dx = tc.y, dy = tc.z;
#pragma unroll
    for (int g = 0; g < 4; ++g) {
      int c = g * 64 + s * 8;
      int cc = g * 64;
      uint4 v00 = *(const uint4*)(c00 + cc);
      uint4 v01 = *(const uint4*)(c00 + dx + cc);
      uint4 v10 = *(const uint4*)(c00 + dy + cc);
      uint4 v11 = *(const uint4*)(c00 + dy + dx + cc);
      const unsigned* a00 = (const unsigned*)&v00;
      const unsigned* a01 = (const unsigned*)&v01;
      const unsigned* a10 = (const unsigned*)&v10;
      const unsigned* a11 = (const unsigned*)&v11;
      uint4 res;
      unsigned* rr = (unsigned*)&res;
#pragma unroll
      for (int q = 0; q < 4; ++q) {
        float lo = w00 * bflo(a00[q]) + w01 * bflo(a01[q]) +
                   w10 * bflo(a10[q]) + w11 * bflo(a11[q]);
        float hi = w00 * bfhi(a00[q]) + w01 * bfhi(a01[q]) +
                   w10 * bfhi(a10[q]) + w11 * bfhi(a11[q]);
        rr[q] = packbf(lo, hi);
      }
      *(uint4*)(arow + kt * 256 + c) = res;
    }
  }
}

// ---------------------------------------------------------------------------
// gemm: FULL-N blocks. C[16384][256] = A[16384][2304] * W^T.
// Block = 64 m-pixels x ALL 256 Cout; grid 256 (= 1 block/CU); A read
// exactly once (no m-tile sharing). 4 waves, wave tile 64x64:
// 32 MFMAs per wave per BK=64 step -> big compute per barrier.
// A: LDS double-buffer 8 KB x 2 (XOR-swizzled, conflict-free).
// B: register-direct from fragment-order wBf (L2-resident 1.18 MB),
// double-buffered one step ahead. One barrier per step.
// Fused bias + bf16 store + GN partial stats.
// ---------------------------------------------------------------------------
__global__ __launch_bounds__(256, 2) void gemm_kernel(
    const unsigned short* __restrict__ A, const unsigned short* __restrict__ wBf,
    const float* __restrict__ bias, unsigned short* __restrict__ cvt,
    float* __restrict__ gstat) {
  __shared__ unsigned short At[2][64 * 64];   // 8 KB per buffer, row pitch 128 B
  int bi = blockIdx.x;                        // m-tile 0..255
  int m0 = bi * 64;
  int t = threadIdx.x, lane = t & 63, wv = t >> 6;
  int lr = lane & 15, lq = lane >> 4;
  int rowq = lane >> 3, pos = lane & 7;
  int swz = pos ^ rowq;

  const char* Asrc0 = (const char*)A + (size_t)(m0 + wv * 16 + rowq) * 4608 + swz * 16;
  const char* Asrc1 = Asrc0 + 8 * 4608;
  // B fragments for this wave's co range [wv*64, wv*64+64): tiles wv*4+tn
  const unsigned short* bb = wBf + ((size_t)(wv * 4) * 64 + lane) * 8;
  // stride per k2 (32 k-elems): 16 tiles * 64 lanes * 8 = 8192 shorts

  f32x4 acc[4][4] = {};
  s16x8 Bf[2][2][4];   // [buf][kh][tn]

  // prologue: stage step 0
  gl2lds16(Asrc0, (char*)At[0] + (wv * 16) * 128);
  gl2lds16(Asrc1, (char*)At[0] + (wv * 16 + 8) * 128);
#pragma unroll
  for (int kh = 0; kh < 2; ++kh)
#pragma unroll
    for (int tn = 0; tn < 4; ++tn)
      Bf[0][kh][tn] = *(const s16x8*)(bb + (size_t)kh * 8192 + tn * 512);

  for (int k = 0; k < 36; ++k) {
    int cur = k & 1, nxt = cur ^ 1;
    __syncthreads();              // staging(k) drained; buf nxt free
    if (k + 1 < 36) {
      int koff = (k + 1) * 128;
      gl2lds16(Asrc0 + koff, (char*)At[nxt] + (wv * 16) * 128);
      gl2lds16(Asrc1 + koff, (char*)At[nxt] + (wv * 16 + 8) * 128);
      int k2b = (k + 1) * 2;
#pragma unroll
      for (int kh = 0; kh < 2; ++kh)
#pragma unroll
        for (int tn = 0; tn < 4; ++tn)
          Bf[nxt][kh][tn] = *(const s16x8*)(bb + (size_t)(k2b + kh) * 8192 + tn * 512);
    }
    const char* buf = (const char*)At[cur];
#pragma unroll
    for (int kh = 0; kh < 2; ++kh) {
      s16x8 af[4];
#pragma unroll
      for (int tm = 0; tm < 4; ++tm) {
        int r = tm * 16 + lr;
        af[tm] = *(const s16x8*)(buf + r * 128 + (((kh * 4 + lq) ^ (r & 7)) * 16));
      }
#pragma unroll
      for (int tm = 0; tm < 4; ++tm)
#pragma unroll
        for (int tn = 0; tn < 4; ++tn)
          acc[tm][tn] = __builtin_amdgcn_mfma_f32_16x16x32_bf16(
              af[tm], Bf[cur][kh][tn], acc[tm][tn], 0, 0, 0);
    }
  }

  // epilogue: m = tm*16 + lq*4 + r (pixel in tile), co = wv*64 + tn*16 + lr
  int b = m0 >> 12;
  int poff = m0 & 4095;
#pragma unroll
  for (int tn = 0; tn < 4; ++tn) {
    int co = wv * 64 + tn * 16 + lr;
    float bco = bias[co];
    unsigned short* cvb = cvt + (size_t)(b * COUT + co) * HW + poff;
    float s = 0.f, q = 0.f;
#pragma unroll
    for (int tm = 0; tm < 4; ++tm) {
      ushort4 st;
#pragma unroll
      for (int r = 0; r < 4; ++r) {
        float v = acc[tm][tn][r] + bco;
        s += v;
        q += v * v;
        ((unsigned short*)&st)[r] = f2bf(v);
      }
      *(ushort4*)(cvb + tm * 16 + lq * 4) = st;
    }
#pragma unroll
    for (int off = 32; off > 0; off >>= 1) {
      s += __shfl_down(s, off, 64);
      q += __shfl_down(q, off, 64);
    }
    if (lane == 0) {
      int g = co >> 4;
      atomicAdd(&gstat[(b * 16 + g) * 2 + 0], s);
      atomicAdd(&gstat[(b * 16 + g) * 2 + 1], q);
    }
  }
}

// ---------------------------------------------------------------------------
// gn_apply: normalize bf16 convout -> f32 out. grid 2048.
// ---------------------------------------------------------------------------
__global__ __launch_bounds__(256) void gn_apply_kernel(
    const unsigned short* __restrict__ convout, const float* __restrict__ gstat,
    const float* __restrict__ gamma, const float* __restrict__ beta,
    float* __restrict__ out) {
  int vid = blockIdx.x * 256 + threadIdx.x;
  int e = vid * 8;
  int b = e >> 20;
  int c = (e >> 12) & 255;
  int g = c >> 4;
  float S = gstat[(b * 16 + g) * 2 + 0];
  float Q = gstat[(b * 16 + g) * 2 + 1];
  float mu = S * (1.f / 65536.f);
  float var = Q * (1.f / 65536.f) - mu * mu;
  float rs = rsqrtf(var + EPS);
  float a = rs * gamma[c];
  float bb = beta[c] - mu * a;
  uint4 v = *(const uint4*)(convout + e);
  const unsigned* u = (const unsigned*)&v;
  float4 o0, o1;
  o0.x = bflo(u[0]) * a + bb;  o0.y = bfhi(u[0]) * a + bb;
  o0.z = bflo(u[1]) * a + bb;  o0.w = bfhi(u[1]) * a + bb;
  o1.x = bflo(u[2]) * a + bb;  o1.y = bfhi(u[2]) * a + bb;
  o1.z = bflo(u[3]) * a + bb;  o1.w = bfhi(u[3]) * a + bb;
  *(float4*)(out + e) = o0;
  *(float4*)(out + e + 4) = o1;
}

// ---------------------------------------------------------------------------
extern "C" void kernel_launch(void* const* d_in, const int* in_sizes, int n_in,
                              void* d_out, int out_size, void* d_ws, size_t ws_size,
                              hipStream_t stream) {
  const float* x      = (const float*)d_in[0];
  const float* w_off  = (const float*)d_in[1];
  const float* b_off  = (const float*)d_in[2];
  const float* weight = (const float*)d_in[3];
  const float* bias   = (const float*)d_in[4];
  const float* gamma  = (const float*)d_in[5];
  const float* beta   = (const float*)d_in[6];
  float* out = (float*)d_out;

  // ws layout (~91 MB): om3 | xT(=cvt alias) | wBf | wOBf | A | gstat
  float* om3 = (float*)d_ws;                                  // 5.31 MB
  unsigned short* xT   = (unsigned short*)(om3 + (size_t)3 * OM3S);  // 8.39 MB
  unsigned short* cvt  = xT;                                  // alias: xT dead after sampler
  unsigned short* wBf  = xT + (size_t)B_ * HW * 256;          // 1.18 MB
  unsigned short* wOBf = wBf + (size_t)COUT * KC;             // 147 KB
  unsigned short* Abuf = wOBf + (size_t)32 * KC;              // 75.5 MB
  float* gstat = (float*)(Abuf + (size_t)B_ * HW * KC);       // 512 B

  prep_kernel<<<dim3(581), dim3(256), 0, stream>>>(x, weight, w_off, xT, wBf, wOBf, gstat);
  offconv_mfma_kernel<<<dim3(768), dim3(256), 0, stream>>>(xT, wOBf, om3);
  sampler_kernel<<<dim3(512), dim3(256), 0, stream>>>(xT, om3, b_off, Abuf);
  gemm_kernel<<<dim3(256), dim3(256), 0, stream>>>(Abuf, wBf, bias, cvt, gstat);
  gn_apply_kernel<<<dim3(2048), dim3(256), 0, stream>>>(cvt, gstat, gamma, beta, out);
}

// Round 12
// 187.612 us; speedup vs baseline: 1.3718x; 1.3718x over previous
//
#include <hip/hip_runtime.h>
#include <math.h>

#define CIN   256
#define COUT  256
#define H     64
#define W     64
#define HW    4096
#define KK    9
#define KC    2304
#define NOFF  27
#define B_    4
#define EPS   1e-5f
#define OM3S  (B_ * NOFF * HW)   // floats per offconv partial buffer

typedef __attribute__((ext_vector_type(4))) float f32x4;
typedef __attribute__((ext_vector_type(8))) short s16x8;

static __device__ __forceinline__ unsigned short f2bf(float f) {
  unsigned u = __builtin_bit_cast(unsigned, f);
  u += 0x7FFF + ((u >> 16) & 1);
  return (unsigned short)(u >> 16);
}
static __device__ __forceinline__ float bflo(unsigned u) {
  return __builtin_bit_cast(float, u << 16);
}
static __device__ __forceinline__ float bfhi(unsigned u) {
  return __builtin_bit_cast(float, u & 0xffff0000u);
}
static __device__ __forceinline__ unsigned packbf(float lo, float hi) {
  unsigned ul = __builtin_bit_cast(unsigned, lo);
  unsigned uh = __builtin_bit_cast(unsigned, hi);
  ul += 0x7FFF + ((ul >> 16) & 1);
  uh += 0x7FFF + ((uh >> 16) & 1);
  return (ul >> 16) | (uh & 0xffff0000u);
}
static __device__ __forceinline__ void gl2lds16(const void* g, void* l) {
  __builtin_amdgcn_global_load_lds(
      (const __attribute__((address_space(1))) unsigned int*)g,
      (__attribute__((address_space(3))) unsigned int*)l, 16, 0, 0);
}

// ---------------------------------------------------------------------------
// prep: fused xprep + weight prep + gstat zero.
//  blocks [0,256):     x NCHW f32 -> xT NHWC bf16
//  blocks [256,544):   wBf main-weight MFMA-B-fragment order:
//                      packet p=(k2*16+tn)*64+lane; elem j: co=tn*16+(lane&15),
//                      k'=k2*32+(lane>>4)*8+j, k'=kt*256+c
//  blocks [544,580):   wOBf offset-weight fragment order (oc>=27 zero)
//  block 580:          zero gstat
// ---------------------------------------------------------------------------
__global__ __launch_bounds__(256) void prep_kernel(
    const float* __restrict__ x, const float* __restrict__ w,
    const float* __restrict__ w_off, unsigned short* __restrict__ xT,
    unsigned short* __restrict__ wBf, unsigned short* __restrict__ wOBf,
    float* __restrict__ gstat) {
  int bi = blockIdx.x;
  int t = threadIdx.x;
  if (bi < 256) {
    __shared__ unsigned short tile[64][272];
    int b = bi >> 6, y = bi & 63;
    const float* src = x + (size_t)b * CIN * HW + y * W;
    for (int r = 0; r < 64; ++r) {
      int idx = r * 256 + t;
      int c = idx >> 6, ww = idx & 63;
      tile[ww][c] = f2bf(src[(size_t)c * HW + ww]);
    }
    __syncthreads();
    unsigned short* dst = xT + ((size_t)(b * 64 + y) * 64) * 256;
    for (int r = 0; r < 8; ++r) {
      int idx = r * 2048 + t * 8;
      int ww = idx >> 8, c = idx & 255;
      *(uint4*)(dst + idx) = *(const uint4*)&tile[ww][c];
    }
  } else if (bi < 544) {
    int pkt = (bi - 256) * 256 + t;        // [0, 73728)
    int lane = pkt & 63;
    int tn = (pkt >> 6) & 15;
    int k2 = pkt >> 10;
    int co = tn * 16 + (lane & 15);
    int kb = k2 * 32 + (lane >> 4) * 8;
    unsigned short v[8];
#pragma unroll
    for (int j = 0; j < 8; ++j) {
      int kk = kb + j;
      int kt = kk >> 8, c = kk & 255;
      v[j] = f2bf(w[(co * 256 + c) * 9 + kt]);
    }
    *(uint4*)&wBf[(size_t)pkt * 8] = *(const uint4*)v;
  } else if (bi < 580) {
    int pkt = (bi - 544) * 256 + t;        // [0, 9216)
    int lane = pkt & 63;
    int tn = (pkt >> 6) & 1;
    int k2 = pkt >> 7;
    int oc = tn * 16 + (lane & 15);
    int kb = k2 * 32 + (lane >> 4) * 8;
    unsigned short v[8];
#pragma unroll
    for (int j = 0; j < 8; ++j) {
      int kk = kb + j;
      int kt = kk >> 8, c = kk & 255;
      v[j] = (oc < NOFF) ? f2bf(w_off[(oc * 256 + c) * 9 + kt]) : (unsigned short)0;
    }
    *(uint4*)&wOBf[(size_t)pkt * 8] = *(const uint4*)v;
  } else {
    if (t < 128) gstat[t] = 0.f;
  }
}

// ---------------------------------------------------------------------------
// offconv: tap-split x3 partials, no LDS/barriers. grid 768.
// ---------------------------------------------------------------------------
__global__ __launch_bounds__(256) void offconv_mfma_kernel(
    const unsigned short* __restrict__ xT, const unsigned short* __restrict__ wOBf,
    float* __restrict__ om3) {
  int bi = blockIdx.x;
  int ts = bi >> 8;
  int row = bi & 255;
  int b = row >> 6, i = row & 63;
  int t = threadIdx.x, lane = t & 63, wv = t >> 6;
  int lr = lane & 15, lq = lane >> 4;
  int p = wv * 16 + lr;
  const unsigned short* xb = xT + (size_t)b * (HW * 256);
  f32x4 acc[2] = {};

  for (int kc = 0; kc < 3; ++kc) {
    int kt = ts * 3 + kc;
    int ky = kt / 3, kx = kt % 3;
    int yy = i - 1 + ky, xx = p - 1 + kx;
    bool ok = ((unsigned)yy < 64u) && ((unsigned)xx < 64u);
    const unsigned short* ap = xb + ((ok ? yy * 64 + xx : 0) << 8) + lq * 8;
#pragma unroll
    for (int c8 = 0; c8 < 8; ++c8) {
      uint4 av = uint4{0, 0, 0, 0};
      if (ok) av = *(const uint4*)(ap + c8 * 32);
      int k2 = kt * 8 + c8;
      s16x8 a = __builtin_bit_cast(s16x8, av);
      s16x8 b0 = *(const s16x8*)(wOBf + ((((k2 * 2 + 0) << 6) | lane) << 3));
      s16x8 b1 = *(const s16x8*)(wOBf + ((((k2 * 2 + 1) << 6) | lane) << 3));
      acc[0] = __builtin_amdgcn_mfma_f32_16x16x32_bf16(a, b0, acc[0], 0, 0, 0);
      acc[1] = __builtin_amdgcn_mfma_f32_16x16x32_bf16(a, b1, acc[1], 0, 0, 0);
    }
  }
#pragma unroll
  for (int tn = 0; tn < 2; ++tn) {
    int oc = tn * 16 + lr;
    if (oc < NOFF) {
      float* ob = om3 + (size_t)ts * OM3S + ((b * NOFF + oc) << 12) + i * 64 + wv * 16;
#pragma unroll
      for (int r = 0; r < 4; ++r) ob[lq * 4 + r] = acc[tn][r];
    }
  }
}

// ---------------------------------------------------------------------------
// sampler: build im2col A[pix][k'] bf16 (k' = kt*256 + c). grid 512.
// ---------------------------------------------------------------------------
__global__ __launch_bounds__(256, 2) void sampler_kernel(
    const unsigned short* __restrict__ xT, const float* __restrict__ om3,
    const float* __restrict__ b_off, unsigned short* __restrict__ Aout) {
  __shared__ float tapw[32][KK][4];
  __shared__ int   tapc[32][KK][4];
  int bi = blockIdx.x;
  int b = bi >> 7, i = (bi >> 1) & 63, j0 = (bi & 1) * 32;
  int t = threadIdx.x;
  const unsigned short* xb = xT + (size_t)b * (HW * 256);

  for (int idx = t; idx < 32 * KK; idx += 256) {
    int p = idx / KK, k = idx % KK;
    int pix = i * 64 + j0 + p;
    size_t o = (size_t)(b * NOFF) * HW + pix;
    float offy = om3[o + k * HW] + om3[OM3S + o + k * HW] +
                 om3[2 * OM3S + o + k * HW] + b_off[k];
    float offx = om3[o + (9 + k) * HW] + om3[OM3S + o + (9 + k) * HW] +
                 om3[2 * OM3S + o + (9 + k) * HW] + b_off[9 + k];
    float mval = om3[o + (18 + k) * HW] + om3[OM3S + o + (18 + k) * HW] +
                 om3[2 * OM3S + o + (18 + k) * HW] + b_off[18 + k];
    float mask = 1.f / (1.f + __expf(-mval));
    float py = (float)(i - 1 + k / 3) + offy;
    float px = (float)(j0 + p - 1 + k % 3) + offx;
    float y0f = floorf(py), x0f = floorf(px);
    float wy1 = py - y0f, wx1 = px - x0f;
    int y0 = (int)y0f, x0 = (int)x0f;
    bool y0ok = (unsigned)y0 < 64u, y1ok = (unsigned)(y0 + 1) < 64u;
    bool x0ok = (unsigned)x0 < 64u, x1ok = (unsigned)(x0 + 1) < 64u;
    tapw[p][k][0] = (1.f - wy1) * (1.f - wx1) * mask * (float)(y0ok && x0ok);
    tapw[p][k][1] = (1.f - wy1) * wx1 * mask * (float)(y0ok && x1ok);
    tapw[p][k][2] = wy1 * (1.f - wx1) * mask * (float)(y1ok && x0ok);
    tapw[p][k][3] = wy1 * wx1 * mask * (float)(y1ok && x1ok);
    int y0c = min(max(y0, 0), 63), y1c = min(max(y0 + 1, 0), 63);
    int x0c = min(max(x0, 0), 63), x1c = min(max(x0 + 1, 0), 63);
    tapc[p][k][0] = (y0c * 64 + x0c) * 256;
    tapc[p][k][1] = (x1c - x0c) * 256;
    tapc[p][k][2] = (y1c - y0c) * 64 * 256;
    tapc[p][k][3] = 0;
  }
  __syncthreads();

  int p = t >> 3, s = t & 7;
  int gpix = b * 4096 + i * 64 + j0 + p;
  unsigned short* arow = Aout + (size_t)gpix * KC;

  for (int kt = 0; kt < KK; ++kt) {
    f32x4 tw = *(const f32x4*)&tapw[p][kt][0];
    float w00 = tw[0], w01 = tw[1], w10 = tw[2], w11 = tw[3];
    int4 tc = *(const int4*)&tapc[p][kt][0];
    const unsigned short* c00 = xb + tc.x + s * 8;
    int dx = tc.y, dy = tc.z;
#pragma unroll
    for (int g = 0; g < 4; ++g) {
      int c = g * 64 + s * 8;
      int cc = g * 64;
      uint4 v00 = *(const uint4*)(c00 + cc);
      uint4 v01 = *(const uint4*)(c00 + dx + cc);
      uint4 v10 = *(const uint4*)(c00 + dy + cc);
      uint4 v11 = *(const uint4*)(c00 + dy + dx + cc);
      const unsigned* a00 = (const unsigned*)&v00;
      const unsigned* a01 = (const unsigned*)&v01;
      const unsigned* a10 = (const unsigned*)&v10;
      const unsigned* a11 = (const unsigned*)&v11;
      uint4 res;
      unsigned* rr = (unsigned*)&res;
#pragma unroll
      for (int q = 0; q < 4; ++q) {
        float lo = w00 * bflo(a00[q]) + w01 * bflo(a01[q]) +
                   w10 * bflo(a10[q]) + w11 * bflo(a11[q]);
        float hi = w00 * bfhi(a00[q]) + w01 * bfhi(a01[q]) +
                   w10 * bfhi(a10[q]) + w11 * bfhi(a11[q]);
        rr[q] = packbf(lo, hi);
      }
      *(uint4*)(arow + kt * 256 + c) = res;
    }
  }
}

// ---------------------------------------------------------------------------
// gemm: FULL-N blocks, spill-free. Block = 64 m-pixels x ALL 256 Cout;
// grid 256 (1 block/CU); A read exactly once. Wave tile 64x64:
// 32 MFMAs per wave per BK=64 step. A: LDS dbuf 8 KB x 2 (XOR swizzle).
// B: register double-buffer from fragment-order wBf — K-loop manually
// unrolled x2 so ALL register-array indices are compile-time constants
// (R11's runtime `Bf[cur]` demoted regs to scratch: 232 MB HBM writes).
// __launch_bounds__(256,1): ~170 VGPR budget OK at 1 wave/SIMD.
// Fused bias + bf16 store + GN partial stats.
// ---------------------------------------------------------------------------
__global__ __launch_bounds__(256, 1) void gemm_kernel(
    const unsigned short* __restrict__ A, const unsigned short* __restrict__ wBf,
    const float* __restrict__ bias, unsigned short* __restrict__ cvt,
    float* __restrict__ gstat) {
  __shared__ unsigned short At[2][64 * 64];   // 8 KB per buffer, row pitch 128 B
  int bi = blockIdx.x;                        // m-tile 0..255
  int m0 = bi * 64;
  int t = threadIdx.x, lane = t & 63, wv = t >> 6;
  int lr = lane & 15, lq = lane >> 4;
  int rowq = lane >> 3, pos = lane & 7;
  int swz = pos ^ rowq;

  const char* Asrc0 = (const char*)A + (size_t)(m0 + wv * 16 + rowq) * 4608 + swz * 16;
  const char* Asrc1 = Asrc0 + 8 * 4608;
  const unsigned short* bb = wBf + ((size_t)(wv * 4) * 64 + lane) * 8;
  // B addr for (k2, tn): bb + k2*8192 + tn*512

  f32x4 acc[4][4] = {};
  s16x8 Bf0[2][4], Bf1[2][4];

  // prologue: stage step 0 (A into buf0, B into Bf0)
  gl2lds16(Asrc0, (char*)At[0] + (wv * 16) * 128);
  gl2lds16(Asrc1, (char*)At[0] + (wv * 16 + 8) * 128);
#pragma unroll
  for (int kh = 0; kh < 2; ++kh)
#pragma unroll
    for (int tn = 0; tn < 4; ++tn)
      Bf0[kh][tn] = *(const s16x8*)(bb + (size_t)kh * 8192 + tn * 512);

#pragma unroll 1
  for (int k = 0; k < 36; k += 2) {
    // ---------- even substep: consume buf0/Bf0, prefetch buf1/Bf1 ----------
    __syncthreads();
    {
      int koff = (k + 1) * 128;               // k+1 <= 35 always
      gl2lds16(Asrc0 + koff, (char*)At[1] + (wv * 16) * 128);
      gl2lds16(Asrc1 + koff, (char*)At[1] + (wv * 16 + 8) * 128);
      int k2b = (k + 1) * 2;
#pragma unroll
      for (int kh = 0; kh < 2; ++kh)
#pragma unroll
        for (int tn = 0; tn < 4; ++tn)
          Bf1[kh][tn] = *(const s16x8*)(bb + (size_t)(k2b + kh) * 8192 + tn * 512);
    }
    {
      const char* buf = (const char*)At[0];
#pragma unroll
      for (int kh = 0; kh < 2; ++kh) {
        s16x8 af[4];
#pragma unroll
        for (int tm = 0; tm < 4; ++tm) {
          int r = tm * 16 + lr;
          af[tm] = *(const s16x8*)(buf + r * 128 + (((kh * 4 + lq) ^ (r & 7)) * 16));
        }
#pragma unroll
        for (int tm = 0; tm < 4; ++tm)
#pragma unroll
          for (int tn = 0; tn < 4; ++tn)
            acc[tm][tn] = __builtin_amdgcn_mfma_f32_16x16x32_bf16(
                af[tm], Bf0[kh][tn], acc[tm][tn], 0, 0, 0);
      }
    }
    // ---------- odd substep: consume buf1/Bf1, prefetch buf0/Bf0 ----------
    __syncthreads();
    if (k + 2 < 36) {
      int koff = (k + 2) * 128;
      gl2lds16(Asrc0 + koff, (char*)At[0] + (wv * 16) * 128);
      gl2lds16(Asrc1 + koff, (char*)At[0] + (wv * 16 + 8) * 128);
      int k2b = (k + 2) * 2;
#pragma unroll
      for (int kh = 0; kh < 2; ++kh)
#pragma unroll
        for (int tn = 0; tn < 4; ++tn)
          Bf0[kh][tn] = *(const s16x8*)(bb + (size_t)(k2b + kh) * 8192 + tn * 512);
    }
    {
      const char* buf = (const char*)At[1];
#pragma unroll
      for (int kh = 0; kh < 2; ++kh) {
        s16x8 af[4];
#pragma unroll
        for (int tm = 0; tm < 4; ++tm) {
          int r = tm * 16 + lr;
          af[tm] = *(const s16x8*)(buf + r * 128 + (((kh * 4 + lq) ^ (r & 7)) * 16));
        }
#pragma unroll
        for (int tm = 0; tm < 4; ++tm)
#pragma unroll
          for (int tn = 0; tn < 4; ++tn)
            acc[tm][tn] = __builtin_amdgcn_mfma_f32_16x16x32_bf16(
                af[tm], Bf1[kh][tn], acc[tm][tn], 0, 0, 0);
      }
    }
  }

  // epilogue: m = tm*16 + lq*4 + r (pixel in tile), co = wv*64 + tn*16 + lr
  int b = m0 >> 12;
  int poff = m0 & 4095;
#pragma unroll
  for (int tn = 0; tn < 4; ++tn) {
    int co = wv * 64 + tn * 16 + lr;
    float bco = bias[co];
    unsigned short* cvb = cvt + (size_t)(b * COUT + co) * HW + poff;
    float s = 0.f, q = 0.f;
#pragma unroll
    for (int tm = 0; tm < 4; ++tm) {
      ushort4 st;
#pragma unroll
      for (int r = 0; r < 4; ++r) {
        float v = acc[tm][tn][r] + bco;
        s += v;
        q += v * v;
        ((unsigned short*)&st)[r] = f2bf(v);
      }
      *(ushort4*)(cvb + tm * 16 + lq * 4) = st;
    }
#pragma unroll
    for (int off = 32; off > 0; off >>= 1) {
      s += __shfl_down(s, off, 64);
      q += __shfl_down(q, off, 64);
    }
    if (lane == 0) {
      int g = co >> 4;
      atomicAdd(&gstat[(b * 16 + g) * 2 + 0], s);
      atomicAdd(&gstat[(b * 16 + g) * 2 + 1], q);
    }
  }
}

// ---------------------------------------------------------------------------
// gn_apply: normalize bf16 convout -> f32 out. grid 2048.
// ---------------------------------------------------------------------------
__global__ __launch_bounds__(256) void gn_apply_kernel(
    const unsigned short* __restrict__ convout, const float* __restrict__ gstat,
    const float* __restrict__ gamma, const float* __restrict__ beta,
    float* __restrict__ out) {
  int vid = blockIdx.x * 256 + threadIdx.x;
  int e = vid * 8;
  int b = e >> 20;
  int c = (e >> 12) & 255;
  int g = c >> 4;
  float S = gstat[(b * 16 + g) * 2 + 0];
  float Q = gstat[(b * 16 + g) * 2 + 1];
  float mu = S * (1.f / 65536.f);
  float var = Q * (1.f / 65536.f) - mu * mu;
  float rs = rsqrtf(var + EPS);
  float a = rs * gamma[c];
  float bb = beta[c] - mu * a;
  uint4 v = *(const uint4*)(convout + e);
  const unsigned* u = (const unsigned*)&v;
  float4 o0, o1;
  o0.x = bflo(u[0]) * a + bb;  o0.y = bfhi(u[0]) * a + bb;
  o0.z = bflo(u[1]) * a + bb;  o0.w = bfhi(u[1]) * a + bb;
  o1.x = bflo(u[2]) * a + bb;  o1.y = bfhi(u[2]) * a + bb;
  o1.z = bflo(u[3]) * a + bb;  o1.w = bfhi(u[3]) * a + bb;
  *(float4*)(out + e) = o0;
  *(float4*)(out + e + 4) = o1;
}

// ---------------------------------------------------------------------------
extern "C" void kernel_launch(void* const* d_in, const int* in_sizes, int n_in,
                              void* d_out, int out_size, void* d_ws, size_t ws_size,
                              hipStream_t stream) {
  const float* x      = (const float*)d_in[0];
  const float* w_off  = (const float*)d_in[1];
  const float* b_off  = (const float*)d_in[2];
  const float* weight = (const float*)d_in[3];
  const float* bias   = (const float*)d_in[4];
  const float* gamma  = (const float*)d_in[5];
  const float* beta   = (const float*)d_in[6];
  float* out = (float*)d_out;

  // ws layout (~91 MB): om3 | xT(=cvt alias) | wBf | wOBf | A | gstat
  float* om3 = (float*)d_ws;                                  // 5.31 MB
  unsigned short* xT   = (unsigned short*)(om3 + (size_t)3 * OM3S);  // 8.39 MB
  unsigned short* cvt  = xT;                                  // alias: xT dead after sampler
  unsigned short* wBf  = xT + (size_t)B_ * HW * 256;          // 1.18 MB
  unsigned short* wOBf = wBf + (size_t)COUT * KC;             // 147 KB
  unsigned short* Abuf = wOBf + (size_t)32 * KC;              // 75.5 MB
  float* gstat = (float*)(Abuf + (size_t)B_ * HW * KC);       // 512 B

  prep_kernel<<<dim3(581), dim3(256), 0, stream>>>(x, weight, w_off, xT, wBf, wOBf, gstat);
  offconv_mfma_kernel<<<dim3(768), dim3(256), 0, stream>>>(xT, wOBf, om3);
  sampler_kernel<<<dim3(512), dim3(256), 0, stream>>>(xT, om3, b_off, Abuf);
  gemm_kernel<<<dim3(256), dim3(256), 0, stream>>>(Abuf, wBf, bias, cvt, gstat);
  gn_apply_kernel<<<dim3(2048), dim3(256), 0, stream>>>(cvt, gstat, gamma, beta, out);
}